// Round 9
// baseline (317.751 us; speedup 1.0000x reference)
//
#include <hip/hip_runtime.h>

#define N_NODES 100000
#define N_EDGES 1600000
#define NBUCK 391   // ceil(N_NODES / 256) buckets of 256 rows
#define NCHUNK 256  // blocks in passes A/C
#define CHUNK 6250  // N_EDGES / NCHUNK exactly
#define LROW 136    // LDS row stride in shorts (272B): optimal bank pattern
#define DCAP 5120   // binD LDS edge capacity (40KB)

typedef float f32x4 __attribute__((ext_vector_type(4)));
typedef _Float16 f16x8 __attribute__((ext_vector_type(8)));
typedef _Float16 h16x2 __attribute__((ext_vector_type(2)));

// fp32 -> f16 bits (RNE). vals in [0,1) give bits <= 0x3BFF (fits 14 bits).
__device__ __forceinline__ unsigned f2h_bits(float f) {
    union { _Float16 h; unsigned short s; } c;
    c.h = (_Float16)f;
    return c.s;
}
__device__ __forceinline__ h16x2 u2h(unsigned u) {
    union { unsigned u; h16x2 h; } c;
    c.u = u;
    return c.h;
}
// pack low/high 16-bit halves of two uints: result low16 = lo's, high16 = hi's
__device__ __forceinline__ unsigned pk16lo(unsigned hi, unsigned lo) {
    return __builtin_amdgcn_perm(hi, lo, 0x05040100u);
}
__device__ __forceinline__ unsigned pk16hi(unsigned hi, unsigned lo) {
    return __builtin_amdgcn_perm(hi, lo, 0x07060302u);
}
__device__ __forceinline__ float fdot2(h16x2 a, h16x2 b, float c) {
#if __has_builtin(__builtin_amdgcn_fdot2)
    return __builtin_amdgcn_fdot2(a, b, c, false);
#else
    return c + (float)a[0] * (float)b[0] + (float)a[1] * (float)b[1];
#endif
}

__device__ __forceinline__ f16x8 pack_h8(float4 a, float4 b) {
    f16x8 r;
    r[0] = (_Float16)a.x; r[1] = (_Float16)a.y;
    r[2] = (_Float16)a.z; r[3] = (_Float16)a.w;
    r[4] = (_Float16)b.x; r[5] = (_Float16)b.y;
    r[6] = (_Float16)b.z; r[7] = (_Float16)b.w;
    return r;
}

// ============ CSR build: bucket binning, zero contended global atomics ======

__global__ __launch_bounds__(256) void k_binA(const int* __restrict__ row,
                                              int* __restrict__ hmat) {
    __shared__ int h[NBUCK];
    for (int i = threadIdx.x; i < NBUCK; i += 256) h[i] = 0;
    __syncthreads();
    int s = blockIdx.x * CHUNK, e = s + CHUNK;
    for (int i = s + threadIdx.x; i < e; i += 256)
        atomicAdd(&h[row[i] >> 8], 1);
    __syncthreads();
    for (int b = threadIdx.x; b < NBUCK; b += 256)
        hmat[blockIdx.x * NBUCK + b] = h[b];
}

__global__ __launch_bounds__(256) void k_colscan(const int* __restrict__ hmat,
                                                 int* __restrict__ bases,
                                                 int* __restrict__ bcnt) {
    __shared__ int s[256];
    int b = blockIdx.x, t = threadIdx.x;
    int v = hmat[t * NBUCK + b];
    s[t] = v;
    __syncthreads();
    for (int off = 1; off < 256; off <<= 1) {
        int x = (t >= off) ? s[t - off] : 0;
        __syncthreads();
        s[t] += x;
        __syncthreads();
    }
    bases[t * NBUCK + b] = s[t] - v;
    if (t == 255) bcnt[b] = s[255];
}

__global__ void k_scanB(const int* __restrict__ bcnt, int* __restrict__ bstart) {
    __shared__ int s[512];
    int t = threadIdx.x;
    int v = (t < NBUCK) ? bcnt[t] : 0;
    s[t] = v;
    __syncthreads();
    for (int off = 1; off < 512; off <<= 1) {
        int x = (t >= off) ? s[t - off] : 0;
        __syncthreads();
        s[t] += x;
        __syncthreads();
    }
    if (t < NBUCK) bstart[t] = s[t] - v;
    if (t == NBUCK) bstart[NBUCK] = N_EDGES;
}

// grouped[i] = {col, (row&255)<<14 | f16bits(val)}
__global__ __launch_bounds__(256) void k_binC(const int* __restrict__ row,
                                              const int* __restrict__ col,
                                              const float* __restrict__ vals,
                                              const int* __restrict__ bstart,
                                              const int* __restrict__ bases,
                                              int2* __restrict__ grouped) {
    __shared__ int cnt[NBUCK];
    for (int i = threadIdx.x; i < NBUCK; i += 256) cnt[i] = 0;
    __syncthreads();
    int s = blockIdx.x * CHUNK, e = s + CHUNK;
    for (int i = s + threadIdx.x; i < e; i += 256) {
        int r = row[i];
        int b = r >> 8;
        int rank = atomicAdd(&cnt[b], 1);
        int pos = bstart[b] + bases[blockIdx.x * NBUCK + b] + rank;
        unsigned hv = f2h_bits(vals[i]);  // <= 0x3BFF for [0,1)
        grouped[pos] = make_int2(col[i], ((r & 255) << 14) | hv);
    }
}

// Pass D: LDS-staged rank-scatter. Final edge word = col<<14 | f16bits(val).
__global__ __launch_bounds__(256) void k_binD(const int2* __restrict__ grouped,
                                              const int* __restrict__ bstart,
                                              unsigned* __restrict__ evf,
                                              int* __restrict__ row_ptr) {
    __shared__ int h[256], sc[256], cur[256];
    __shared__ int2 ebuf[DCAP];
    int b = blockIdx.x, t = threadIdx.x;
    int s0 = bstart[b], e0 = bstart[b + 1];
    int n = e0 - s0;
    bool inlds = (n <= DCAP);
    h[t] = 0;
    __syncthreads();
    if (inlds) {
        for (int i = t; i < n; i += 256) ebuf[i] = grouped[s0 + i];
        __syncthreads();
        for (int i = t; i < n; i += 256)
            atomicAdd(&h[(ebuf[i].y >> 14) & 255], 1);
    } else {
        for (int i = s0 + t; i < e0; i += 256)
            atomicAdd(&h[(grouped[i].y >> 14) & 255], 1);
    }
    __syncthreads();
    int v = h[t];
    sc[t] = v;
    __syncthreads();
    for (int off = 1; off < 256; off <<= 1) {
        int x = (t >= off) ? sc[t - off] : 0;
        __syncthreads();
        sc[t] += x;
        __syncthreads();
    }
    int excl = sc[t] - v;
    cur[t] = excl;
    int grow = b * 256 + t;
    if (grow <= N_NODES) row_ptr[grow] = s0 + excl;
    __syncthreads();
    if (inlds) {
        for (int i = t; i < n; i += 256) {
            int2 g = ebuf[i];
            int rl = (g.y >> 14) & 255;
            int p = atomicAdd(&cur[rl], 1);
            evf[s0 + p] = ((unsigned)g.x << 14) | (unsigned)(g.y & 0x3fff);
        }
    } else {
        for (int i = s0 + t; i < e0; i += 256) {
            int2 g = grouped[i];
            int rl = (g.y >> 14) & 255;
            int p = atomicAdd(&cur[rl], 1);
            evf[s0 + p] = ((unsigned)g.x << 14) | (unsigned)(g.y & 0x3fff);
        }
    }
}

// ---------------- weight convert+transpose: Wt[n][k] = f16(W[k][n]) --------
__global__ void k_cvtw3(const float* __restrict__ Wa, const float* __restrict__ Wb,
                        const float* __restrict__ Wc, unsigned short* __restrict__ Wta,
                        unsigned short* __restrict__ Wtb, unsigned short* __restrict__ Wtc) {
    int t = blockIdx.x * 256 + threadIdx.x;
    int which = t >> 14;
    int i = t & 16383;
    int n = i & 127, k = i >> 7;
    const float* W = which == 0 ? Wa : which == 1 ? Wb : Wc;
    unsigned short* Wt = which == 0 ? Wta : which == 1 ? Wtb : Wtc;
    Wt[n * 128 + k] = (unsigned short)f2h_bits(W[k * 128 + n]);
}

// -------- GEMM1: H(f16) = relu(X @ W_in + b_in), f16 MFMA ------------------
__global__ __launch_bounds__(256) void k_gemm_in(const float* __restrict__ X,
                                                 const unsigned short* __restrict__ Wt,
                                                 const float* __restrict__ b,
                                                 unsigned short* __restrict__ H) {
    __shared__ unsigned short lds[64 * LROW];
    int tid = threadIdx.x;
    int lane = tid & 63, wv = tid >> 6;
    int quad = lane >> 4, c16 = lane & 15;

    f16x8 wf[2][4];
    float bb[2];
#pragma unroll
    for (int nt = 0; nt < 2; nt++) {
        int ng = wv * 2 + nt;
        bb[nt] = b[ng * 16 + c16];
#pragma unroll
        for (int kc = 0; kc < 4; kc++)
            wf[nt][kc] = *(const f16x8*)&Wt[(ng * 16 + c16) * 128 + kc * 32 + quad * 8];
    }

    int tilebase = blockIdx.x * 64;
    const float4* Xg = (const float4*)X;
#pragma unroll
    for (int i = 0; i < 4; i++) {
        int c = tid + i * 256;
        int r = c >> 4, o = c & 15;
        int grow = tilebase + r;
        float4 f0 = make_float4(0.f, 0.f, 0.f, 0.f), f1 = f0;
        if (grow < N_NODES) {
            f0 = Xg[(size_t)grow * 32 + o * 2];
            f1 = Xg[(size_t)grow * 32 + o * 2 + 1];
        }
        *(f16x8*)&lds[r * LROW + o * 8] = pack_h8(f0, f1);
    }
    __syncthreads();

    f32x4 acc[4][2] = {};
#pragma unroll
    for (int t4 = 0; t4 < 4; t4++) {
#pragma unroll
        for (int kc = 0; kc < 4; kc++) {
            f16x8 af = *(const f16x8*)&lds[(t4 * 16 + c16) * LROW + kc * 32 + quad * 8];
#pragma unroll
            for (int nt = 0; nt < 2; nt++)
                acc[t4][nt] = __builtin_amdgcn_mfma_f32_16x16x32_f16(af, wf[nt][kc],
                                                                    acc[t4][nt], 0, 0, 0);
        }
    }
    __syncthreads();

#pragma unroll
    for (int t4 = 0; t4 < 4; t4++)
#pragma unroll
        for (int nt = 0; nt < 2; nt++) {
            int ncol = (wv * 2 + nt) * 16 + c16;
#pragma unroll
            for (int r = 0; r < 4; r++) {
                float v = fmaxf(acc[t4][nt][r] + bb[nt], 0.f);
                lds[(t4 * 16 + quad * 4 + r) * LROW + ncol] = (unsigned short)f2h_bits(v);
            }
        }
    __syncthreads();
#pragma unroll
    for (int i = 0; i < 4; i++) {
        int c = tid + i * 256;
        int r = c >> 4, o = c & 15;
        int grow = tilebase + r;
        if (grow < N_NODES)
            *(uint4*)&H[(size_t)grow * 128 + o * 8] = *(const uint4*)&lds[r * LROW + o * 8];
    }
}

// ------- SpMM: wave/row, quarter-wave/edge, 16 edges/round, v_dot2_f32_f16 --
// evf word = col<<14 | f16bits(val). Pair edges in-lane; v_perm packs
// {h_a,h_b} half2; one dot2 = 2 FMAs with fp32 accumulate.
__global__ __launch_bounds__(256) void k_spmm(const int* __restrict__ rp,
                                              const unsigned* __restrict__ evf,
                                              const unsigned* __restrict__ Hin,
                                              unsigned* __restrict__ Ho) {
    int wid = (blockIdx.x * blockDim.x + threadIdx.x) >> 6;
    int lane = threadIdx.x & 63;
    if (wid >= N_NODES) return;
    int q = lane >> 4, l16 = lane & 15;
    int s = __builtin_amdgcn_readfirstlane(rp[wid]);
    int e = __builtin_amdgcn_readfirstlane(rp[wid + 1]);
    float a0 = 0.f, a1 = 0.f, a2 = 0.f, a3 = 0.f;
    float a4 = 0.f, a5 = 0.f, a6 = 0.f, a7 = 0.f;
    int j = s;
    for (; j + 16 <= e; j += 16) {
        unsigned u0 = evf[j + q];
        unsigned u1 = evf[j + 4 + q];
        unsigned u2 = evf[j + 8 + q];
        unsigned u3 = evf[j + 12 + q];
        const uint4 h0 = *(const uint4*)&Hin[(size_t)(u0 >> 14) * 64 + l16 * 4];
        const uint4 h1 = *(const uint4*)&Hin[(size_t)(u1 >> 14) * 64 + l16 * 4];
        const uint4 h2 = *(const uint4*)&Hin[(size_t)(u2 >> 14) * 64 + l16 * 4];
        const uint4 h3 = *(const uint4*)&Hin[(size_t)(u3 >> 14) * 64 + l16 * 4];
        h16x2 v01 = u2h(pk16lo(u1 & 0x3fffu, u0 & 0x3fffu));
        h16x2 v23 = u2h(pk16lo(u3 & 0x3fffu, u2 & 0x3fffu));
        a0 = fdot2(v01, u2h(pk16lo(h1.x, h0.x)), a0);
        a0 = fdot2(v23, u2h(pk16lo(h3.x, h2.x)), a0);
        a1 = fdot2(v01, u2h(pk16hi(h1.x, h0.x)), a1);
        a1 = fdot2(v23, u2h(pk16hi(h3.x, h2.x)), a1);
        a2 = fdot2(v01, u2h(pk16lo(h1.y, h0.y)), a2);
        a2 = fdot2(v23, u2h(pk16lo(h3.y, h2.y)), a2);
        a3 = fdot2(v01, u2h(pk16hi(h1.y, h0.y)), a3);
        a3 = fdot2(v23, u2h(pk16hi(h3.y, h2.y)), a3);
        a4 = fdot2(v01, u2h(pk16lo(h1.z, h0.z)), a4);
        a4 = fdot2(v23, u2h(pk16lo(h3.z, h2.z)), a4);
        a5 = fdot2(v01, u2h(pk16hi(h1.z, h0.z)), a5);
        a5 = fdot2(v23, u2h(pk16hi(h3.z, h2.z)), a5);
        a6 = fdot2(v01, u2h(pk16lo(h1.w, h0.w)), a6);
        a6 = fdot2(v23, u2h(pk16lo(h3.w, h2.w)), a6);
        a7 = fdot2(v01, u2h(pk16hi(h1.w, h0.w)), a7);
        a7 = fdot2(v23, u2h(pk16hi(h3.w, h2.w)), a7);
    }
    if (j < e) {
        int i0 = j + q, i1 = j + 4 + q, i2 = j + 8 + q, i3 = j + 12 + q;
        unsigned u0 = evf[i0 < e ? i0 : e - 1];
        unsigned u1 = evf[i1 < e ? i1 : e - 1];
        unsigned u2 = evf[i2 < e ? i2 : e - 1];
        unsigned u3 = evf[i3 < e ? i3 : e - 1];
        const uint4 h0 = *(const uint4*)&Hin[(size_t)(u0 >> 14) * 64 + l16 * 4];
        const uint4 h1 = *(const uint4*)&Hin[(size_t)(u1 >> 14) * 64 + l16 * 4];
        const uint4 h2 = *(const uint4*)&Hin[(size_t)(u2 >> 14) * 64 + l16 * 4];
        const uint4 h3 = *(const uint4*)&Hin[(size_t)(u3 >> 14) * 64 + l16 * 4];
        unsigned m0 = (i0 < e) ? (u0 & 0x3fffu) : 0u;
        unsigned m1 = (i1 < e) ? (u1 & 0x3fffu) : 0u;
        unsigned m2 = (i2 < e) ? (u2 & 0x3fffu) : 0u;
        unsigned m3 = (i3 < e) ? (u3 & 0x3fffu) : 0u;
        h16x2 v01 = u2h(pk16lo(m1, m0));
        h16x2 v23 = u2h(pk16lo(m3, m2));
        a0 = fdot2(v01, u2h(pk16lo(h1.x, h0.x)), a0);
        a0 = fdot2(v23, u2h(pk16lo(h3.x, h2.x)), a0);
        a1 = fdot2(v01, u2h(pk16hi(h1.x, h0.x)), a1);
        a1 = fdot2(v23, u2h(pk16hi(h3.x, h2.x)), a1);
        a2 = fdot2(v01, u2h(pk16lo(h1.y, h0.y)), a2);
        a2 = fdot2(v23, u2h(pk16lo(h3.y, h2.y)), a2);
        a3 = fdot2(v01, u2h(pk16hi(h1.y, h0.y)), a3);
        a3 = fdot2(v23, u2h(pk16hi(h3.y, h2.y)), a3);
        a4 = fdot2(v01, u2h(pk16lo(h1.z, h0.z)), a4);
        a4 = fdot2(v23, u2h(pk16lo(h3.z, h2.z)), a4);
        a5 = fdot2(v01, u2h(pk16hi(h1.z, h0.z)), a5);
        a5 = fdot2(v23, u2h(pk16hi(h3.z, h2.z)), a5);
        a6 = fdot2(v01, u2h(pk16lo(h1.w, h0.w)), a6);
        a6 = fdot2(v23, u2h(pk16lo(h3.w, h2.w)), a6);
        a7 = fdot2(v01, u2h(pk16hi(h1.w, h0.w)), a7);
        a7 = fdot2(v23, u2h(pk16hi(h3.w, h2.w)), a7);
    }
    a0 += __shfl_xor(a0, 16, 64); a0 += __shfl_xor(a0, 32, 64);
    a1 += __shfl_xor(a1, 16, 64); a1 += __shfl_xor(a1, 32, 64);
    a2 += __shfl_xor(a2, 16, 64); a2 += __shfl_xor(a2, 32, 64);
    a3 += __shfl_xor(a3, 16, 64); a3 += __shfl_xor(a3, 32, 64);
    a4 += __shfl_xor(a4, 16, 64); a4 += __shfl_xor(a4, 32, 64);
    a5 += __shfl_xor(a5, 16, 64); a5 += __shfl_xor(a5, 32, 64);
    a6 += __shfl_xor(a6, 16, 64); a6 += __shfl_xor(a6, 32, 64);
    a7 += __shfl_xor(a7, 16, 64); a7 += __shfl_xor(a7, 32, 64);
    if (q == 0) {
        uint4 p;
        p.x = (f2h_bits(a1) << 16) | f2h_bits(a0);
        p.y = (f2h_bits(a3) << 16) | f2h_bits(a2);
        p.z = (f2h_bits(a5) << 16) | f2h_bits(a4);
        p.w = (f2h_bits(a7) << 16) | f2h_bits(a6);
        *(uint4*)&Ho[(size_t)wid * 64 + l16 * 4] = p;
    }
}

// ------- Final: out = relu(AH@W1 + A2H@W2) @ W_out + b_out, f16 MFMA --------
__global__ __launch_bounds__(256) void k_gemm_out(const unsigned short* __restrict__ AH,
                                                  const unsigned short* __restrict__ A2H,
                                                  const unsigned short* __restrict__ Wt1,
                                                  const unsigned short* __restrict__ Wt2,
                                                  const float* __restrict__ Wout,
                                                  const float* __restrict__ bout,
                                                  float* __restrict__ out) {
    __shared__ unsigned short lds[2][64 * LROW];
    __shared__ float part[4][64];
    int tid = threadIdx.x;
    int lane = tid & 63, wv = tid >> 6;
    int quad = lane >> 4, c16 = lane & 15;

    f16x8 w1f[2][4], w2f[2][4];
    float wo[2];
#pragma unroll
    for (int nt = 0; nt < 2; nt++) {
        int ng = wv * 2 + nt;
        wo[nt] = Wout[ng * 16 + c16];
#pragma unroll
        for (int kc = 0; kc < 4; kc++) {
            w1f[nt][kc] = *(const f16x8*)&Wt1[(ng * 16 + c16) * 128 + kc * 32 + quad * 8];
            w2f[nt][kc] = *(const f16x8*)&Wt2[(ng * 16 + c16) * 128 + kc * 32 + quad * 8];
        }
    }
    float bo = bout[0];

    int tilebase = blockIdx.x * 64;
    const uint4* Ag = (const uint4*)(AH + (size_t)tilebase * 128);
    const uint4* Bg = (const uint4*)(A2H + (size_t)tilebase * 128);
#pragma unroll
    for (int i = 0; i < 4; i++) {
        int c = tid + i * 256;
        int r = c >> 4, o = c & 15;
        *(uint4*)&lds[0][r * LROW + o * 8] = Ag[c];
        *(uint4*)&lds[1][r * LROW + o * 8] = Bg[c];
    }
    __syncthreads();

    f32x4 acc[4][2] = {};
#pragma unroll
    for (int t4 = 0; t4 < 4; t4++) {
#pragma unroll
        for (int kc = 0; kc < 4; kc++) {
            f16x8 afA = *(const f16x8*)&lds[0][(t4 * 16 + c16) * LROW + kc * 32 + quad * 8];
            f16x8 afB = *(const f16x8*)&lds[1][(t4 * 16 + c16) * LROW + kc * 32 + quad * 8];
#pragma unroll
            for (int nt = 0; nt < 2; nt++) {
                acc[t4][nt] = __builtin_amdgcn_mfma_f32_16x16x32_f16(afA, w1f[nt][kc],
                                                                    acc[t4][nt], 0, 0, 0);
                acc[t4][nt] = __builtin_amdgcn_mfma_f32_16x16x32_f16(afB, w2f[nt][kc],
                                                                    acc[t4][nt], 0, 0, 0);
            }
        }
    }

#pragma unroll
    for (int t4 = 0; t4 < 4; t4++) {
        float p[4];
#pragma unroll
        for (int r = 0; r < 4; r++)
            p[r] = fmaxf(acc[t4][0][r], 0.f) * wo[0] + fmaxf(acc[t4][1][r], 0.f) * wo[1];
#pragma unroll
        for (int m = 1; m < 16; m <<= 1)
#pragma unroll
            for (int r = 0; r < 4; r++) p[r] += __shfl_xor(p[r], m, 64);
        if (c16 == 0)
#pragma unroll
            for (int r = 0; r < 4; r++) part[wv][t4 * 16 + quad * 4 + r] = p[r];
    }
    __syncthreads();
    if (tid < 64) {
        int orow = tilebase + tid;
        if (orow < N_NODES)
            out[orow] = part[0][tid] + part[1][tid] + part[2][tid] + part[3][tid] + bo;
    }
}

// ---------------- launch ----------------

extern "C" void kernel_launch(void* const* d_in, const int* in_sizes, int n_in,
                              void* d_out, int out_size, void* d_ws, size_t ws_size,
                              hipStream_t stream) {
    const float* X    = (const float*)d_in[0];
    const int*   row  = (const int*)d_in[1];
    const int*   col  = (const int*)d_in[2];
    const float* vals = (const float*)d_in[3];
    const float* W_in = (const float*)d_in[4];
    const float* b_in = (const float*)d_in[5];
    const float* W1   = (const float*)d_in[6];
    const float* W2   = (const float*)d_in[7];
    const float* Wout = (const float*)d_in[8];
    const float* bout = (const float*)d_in[9];
    float* out = (float*)d_out;

    char* ws = (char*)d_ws;
    size_t off = 0;
    auto alloc = [&](size_t bytes) -> void* {
        void* p = ws + off;
        off += (bytes + 511) & ~(size_t)511;
        return p;
    };
    unsigned short* Hb  = (unsigned short*)alloc((size_t)N_NODES * 128 * 2);  // H f16
    unsigned short* AHb = (unsigned short*)alloc((size_t)N_NODES * 128 * 2);  // AH f16
    unsigned short* A2b = (unsigned short*)alloc((size_t)N_NODES * 128 * 2);  // A2H f16
    unsigned* evf  = (unsigned*)alloc((size_t)N_EDGES * 4);
    int2* grouped  = (int2*)alloc((size_t)N_EDGES * 8);
    unsigned short* Wtin = (unsigned short*)alloc(128 * 128 * 2);
    unsigned short* Wt1  = (unsigned short*)alloc(128 * 128 * 2);
    unsigned short* Wt2  = (unsigned short*)alloc(128 * 128 * 2);
    int*   hmat    = (int*)alloc((size_t)NCHUNK * NBUCK * 4);
    int*   bases   = (int*)alloc((size_t)NCHUNK * NBUCK * 4);
    int*   bcnt    = (int*)alloc(512 * 4);
    int*   bstart  = (int*)alloc(512 * 4);
    int*   row_ptr = (int*)alloc((size_t)(N_NODES + 256) * 4);

    k_binA<<<NCHUNK, 256, 0, stream>>>(row, hmat);
    k_colscan<<<NBUCK, 256, 0, stream>>>(hmat, bases, bcnt);
    k_scanB<<<1, 512, 0, stream>>>(bcnt, bstart);
    k_binC<<<NCHUNK, 256, 0, stream>>>(row, col, vals, bstart, bases, grouped);
    k_binD<<<NBUCK, 256, 0, stream>>>(grouped, bstart, evf, row_ptr);

    k_cvtw3<<<192, 256, 0, stream>>>(W_in, W1, W2, Wtin, Wt1, Wt2);

    int gblk = (N_NODES + 63) / 64;  // 1563
    k_gemm_in<<<gblk, 256, 0, stream>>>(X, Wtin, b_in, Hb);

    int sblk = (N_NODES + 3) / 4;  // 4 waves/block, 1 row/wave
    k_spmm<<<sblk, 256, 0, stream>>>(row_ptr, evf, (const unsigned*)Hb, (unsigned*)AHb);
    k_spmm<<<sblk, 256, 0, stream>>>(row_ptr, evf, (const unsigned*)AHb, (unsigned*)A2b);

    k_gemm_out<<<gblk, 256, 0, stream>>>(AHb, A2b, Wt1, Wt2, Wout, bout, out);
}

// Round 10
// 296.461 us; speedup vs baseline: 1.0718x; 1.0718x over previous
//
#include <hip/hip_runtime.h>

#define N_NODES 100000
#define N_EDGES 1600000
#define NBUCK 391   // ceil(N_NODES / 256) buckets of 256 rows
#define NCHUNK 256  // blocks in passes A/C
#define CHUNK 6250  // N_EDGES / NCHUNK exactly
#define LROW 136    // LDS row stride in shorts (272B): optimal bank pattern
#define DCAP 5120   // binD LDS edge capacity (40KB)

typedef float f32x4 __attribute__((ext_vector_type(4)));
typedef _Float16 f16x8 __attribute__((ext_vector_type(8)));
typedef _Float16 h16x2 __attribute__((ext_vector_type(2)));

// fp32 -> f16 bits (RNE). vals in [0,1) give bits <= 0x3BFF (fits 14 bits).
__device__ __forceinline__ unsigned f2h_bits(float f) {
    union { _Float16 h; unsigned short s; } c;
    c.h = (_Float16)f;
    return c.s;
}
__device__ __forceinline__ h16x2 u2h(unsigned u) {
    union { unsigned u; h16x2 h; } c;
    c.u = u;
    return c.h;
}
// pack low/high 16-bit halves of two uints: result low16 = lo's, high16 = hi's
__device__ __forceinline__ unsigned pk16lo(unsigned hi, unsigned lo) {
    return __builtin_amdgcn_perm(hi, lo, 0x05040100u);
}
__device__ __forceinline__ unsigned pk16hi(unsigned hi, unsigned lo) {
    return __builtin_amdgcn_perm(hi, lo, 0x07060302u);
}
__device__ __forceinline__ float fdot2(h16x2 a, h16x2 b, float c) {
#if __has_builtin(__builtin_amdgcn_fdot2)
    return __builtin_amdgcn_fdot2(a, b, c, false);
#else
    return c + (float)a[0] * (float)b[0] + (float)a[1] * (float)b[1];
#endif
}

__device__ __forceinline__ f16x8 pack_h8(float4 a, float4 b) {
    f16x8 r;
    r[0] = (_Float16)a.x; r[1] = (_Float16)a.y;
    r[2] = (_Float16)a.z; r[3] = (_Float16)a.w;
    r[4] = (_Float16)b.x; r[5] = (_Float16)b.y;
    r[6] = (_Float16)b.z; r[7] = (_Float16)b.w;
    return r;
}

// ============ CSR build: bucket binning, zero contended global atomics ======

// Merged: blocks [0,NCHUNK) = per-chunk bucket histogram (binA);
// blocks [NCHUNK, NCHUNK+192) = weight convert+transpose (cvtw3).
__global__ __launch_bounds__(256) void k_prep(const int* __restrict__ row,
                                              int* __restrict__ hmat,
                                              const float* __restrict__ Wa,
                                              const float* __restrict__ Wb,
                                              const float* __restrict__ Wc,
                                              unsigned short* __restrict__ Wta,
                                              unsigned short* __restrict__ Wtb,
                                              unsigned short* __restrict__ Wtc) {
    if (blockIdx.x < NCHUNK) {
        __shared__ int h[NBUCK];
        for (int i = threadIdx.x; i < NBUCK; i += 256) h[i] = 0;
        __syncthreads();
        int s = blockIdx.x * CHUNK, e = s + CHUNK;
        for (int i = s + threadIdx.x; i < e; i += 256)
            atomicAdd(&h[row[i] >> 8], 1);
        __syncthreads();
        for (int b = threadIdx.x; b < NBUCK; b += 256)
            hmat[blockIdx.x * NBUCK + b] = h[b];
    } else {
        int t = (blockIdx.x - NCHUNK) * 256 + threadIdx.x;
        int which = t >> 14;
        int i = t & 16383;
        int n = i & 127, k = i >> 7;
        const float* W = which == 0 ? Wa : which == 1 ? Wb : Wc;
        unsigned short* Wt = which == 0 ? Wta : which == 1 ? Wtb : Wtc;
        Wt[n * 128 + k] = (unsigned short)f2h_bits(W[k * 128 + n]);
    }
}

// Merged: blocks [0,NBUCK) = per-bucket exclusive scan over chunks (bases);
// block NBUCK = bucket totals + exclusive scan -> bstart.
__global__ __launch_bounds__(512) void k_colscanB(const int* __restrict__ hmat,
                                                  int* __restrict__ bases,
                                                  int* __restrict__ bstart) {
    __shared__ int s[512];
    int b = blockIdx.x, t = threadIdx.x;
    if (b < NBUCK) {
        int v = (t < NCHUNK) ? hmat[t * NBUCK + b] : 0;
        s[t] = v;
        __syncthreads();
        for (int off = 1; off < 512; off <<= 1) {
            int x = (t >= off) ? s[t - off] : 0;
            __syncthreads();
            s[t] += x;
            __syncthreads();
        }
        if (t < NCHUNK) bases[t * NBUCK + b] = s[t] - v;
    } else {
        int v = 0;
        if (t < NBUCK) {
            for (int blk = 0; blk < NCHUNK; blk++) v += hmat[blk * NBUCK + t];
        }
        s[t] = v;
        __syncthreads();
        for (int off = 1; off < 512; off <<= 1) {
            int x = (t >= off) ? s[t - off] : 0;
            __syncthreads();
            s[t] += x;
            __syncthreads();
        }
        if (t < NBUCK) bstart[t] = s[t] - v;
        if (t == NBUCK) bstart[NBUCK] = N_EDGES;
    }
}

// grouped[i] = {col, (row&255)<<14 | f16bits(val)}
__global__ __launch_bounds__(256) void k_binC(const int* __restrict__ row,
                                              const int* __restrict__ col,
                                              const float* __restrict__ vals,
                                              const int* __restrict__ bstart,
                                              const int* __restrict__ bases,
                                              int2* __restrict__ grouped) {
    __shared__ int cnt[NBUCK];
    for (int i = threadIdx.x; i < NBUCK; i += 256) cnt[i] = 0;
    __syncthreads();
    int s = blockIdx.x * CHUNK, e = s + CHUNK;
    for (int i = s + threadIdx.x; i < e; i += 256) {
        int r = row[i];
        int b = r >> 8;
        int rank = atomicAdd(&cnt[b], 1);
        int pos = bstart[b] + bases[blockIdx.x * NBUCK + b] + rank;
        unsigned hv = f2h_bits(vals[i]);  // <= 0x3BFF for [0,1)
        grouped[pos] = make_int2(col[i], ((r & 255) << 14) | hv);
    }
}

// Pass D: LDS-staged rank-scatter. Final edge word = col<<14 | f16bits(val).
__global__ __launch_bounds__(256) void k_binD(const int2* __restrict__ grouped,
                                              const int* __restrict__ bstart,
                                              unsigned* __restrict__ evf,
                                              int* __restrict__ row_ptr) {
    __shared__ int h[256], sc[256], cur[256];
    __shared__ int2 ebuf[DCAP];
    int b = blockIdx.x, t = threadIdx.x;
    int s0 = bstart[b], e0 = bstart[b + 1];
    int n = e0 - s0;
    bool inlds = (n <= DCAP);
    h[t] = 0;
    __syncthreads();
    if (inlds) {
        for (int i = t; i < n; i += 256) ebuf[i] = grouped[s0 + i];
        __syncthreads();
        for (int i = t; i < n; i += 256)
            atomicAdd(&h[(ebuf[i].y >> 14) & 255], 1);
    } else {
        for (int i = s0 + t; i < e0; i += 256)
            atomicAdd(&h[(grouped[i].y >> 14) & 255], 1);
    }
    __syncthreads();
    int v = h[t];
    sc[t] = v;
    __syncthreads();
    for (int off = 1; off < 256; off <<= 1) {
        int x = (t >= off) ? sc[t - off] : 0;
        __syncthreads();
        sc[t] += x;
        __syncthreads();
    }
    int excl = sc[t] - v;
    cur[t] = excl;
    int grow = b * 256 + t;
    if (grow <= N_NODES) row_ptr[grow] = s0 + excl;
    __syncthreads();
    if (inlds) {
        for (int i = t; i < n; i += 256) {
            int2 g = ebuf[i];
            int rl = (g.y >> 14) & 255;
            int p = atomicAdd(&cur[rl], 1);
            evf[s0 + p] = ((unsigned)g.x << 14) | (unsigned)(g.y & 0x3fff);
        }
    } else {
        for (int i = s0 + t; i < e0; i += 256) {
            int2 g = grouped[i];
            int rl = (g.y >> 14) & 255;
            int p = atomicAdd(&cur[rl], 1);
            evf[s0 + p] = ((unsigned)g.x << 14) | (unsigned)(g.y & 0x3fff);
        }
    }
}

// -------- GEMM1: H(f16) = relu(X @ W_in + b_in), f16 MFMA ------------------
__global__ __launch_bounds__(256) void k_gemm_in(const float* __restrict__ X,
                                                 const unsigned short* __restrict__ Wt,
                                                 const float* __restrict__ b,
                                                 unsigned short* __restrict__ H) {
    __shared__ unsigned short lds[64 * LROW];
    int tid = threadIdx.x;
    int lane = tid & 63, wv = tid >> 6;
    int quad = lane >> 4, c16 = lane & 15;

    f16x8 wf[2][4];
    float bb[2];
#pragma unroll
    for (int nt = 0; nt < 2; nt++) {
        int ng = wv * 2 + nt;
        bb[nt] = b[ng * 16 + c16];
#pragma unroll
        for (int kc = 0; kc < 4; kc++)
            wf[nt][kc] = *(const f16x8*)&Wt[(ng * 16 + c16) * 128 + kc * 32 + quad * 8];
    }

    int tilebase = blockIdx.x * 64;
    const float4* Xg = (const float4*)X;
#pragma unroll
    for (int i = 0; i < 4; i++) {
        int c = tid + i * 256;
        int r = c >> 4, o = c & 15;
        int grow = tilebase + r;
        float4 f0 = make_float4(0.f, 0.f, 0.f, 0.f), f1 = f0;
        if (grow < N_NODES) {
            f0 = Xg[(size_t)grow * 32 + o * 2];
            f1 = Xg[(size_t)grow * 32 + o * 2 + 1];
        }
        *(f16x8*)&lds[r * LROW + o * 8] = pack_h8(f0, f1);
    }
    __syncthreads();

    f32x4 acc[4][2] = {};
#pragma unroll
    for (int t4 = 0; t4 < 4; t4++) {
#pragma unroll
        for (int kc = 0; kc < 4; kc++) {
            f16x8 af = *(const f16x8*)&lds[(t4 * 16 + c16) * LROW + kc * 32 + quad * 8];
#pragma unroll
            for (int nt = 0; nt < 2; nt++)
                acc[t4][nt] = __builtin_amdgcn_mfma_f32_16x16x32_f16(af, wf[nt][kc],
                                                                    acc[t4][nt], 0, 0, 0);
        }
    }
    __syncthreads();

#pragma unroll
    for (int t4 = 0; t4 < 4; t4++)
#pragma unroll
        for (int nt = 0; nt < 2; nt++) {
            int ncol = (wv * 2 + nt) * 16 + c16;
#pragma unroll
            for (int r = 0; r < 4; r++) {
                float v = fmaxf(acc[t4][nt][r] + bb[nt], 0.f);
                lds[(t4 * 16 + quad * 4 + r) * LROW + ncol] = (unsigned short)f2h_bits(v);
            }
        }
    __syncthreads();
#pragma unroll
    for (int i = 0; i < 4; i++) {
        int c = tid + i * 256;
        int r = c >> 4, o = c & 15;
        int grow = tilebase + r;
        if (grow < N_NODES)
            *(uint4*)&H[(size_t)grow * 128 + o * 8] = *(const uint4*)&lds[r * LROW + o * 8];
    }
}

// ------- SpMM: wave/row; row's edge words preloaded wave-wide (one coalesced
// load), distributed to rounds via __shfl (no per-round dependent evf load).
// Quarter-wave per edge, 16 edges/round, v_dot2_f32_f16, fp32 accumulate.
__global__ __launch_bounds__(256) void k_spmm(const int* __restrict__ rp,
                                              const unsigned* __restrict__ evf,
                                              const unsigned* __restrict__ Hin,
                                              unsigned* __restrict__ Ho) {
    int wid = (blockIdx.x * blockDim.x + threadIdx.x) >> 6;
    int lane = threadIdx.x & 63;
    if (wid >= N_NODES) return;
    int q = lane >> 4, l16 = lane & 15;
    int s = __builtin_amdgcn_readfirstlane(rp[wid]);
    int e = __builtin_amdgcn_readfirstlane(rp[wid + 1]);
    float a0 = 0.f, a1 = 0.f, a2 = 0.f, a3 = 0.f;
    float a4 = 0.f, a5 = 0.f, a6 = 0.f, a7 = 0.f;
    for (int base = s; base < e; base += 64) {
        int cnt = e - base;
        if (cnt > 64) cnt = 64;
        unsigned ev = evf[base + (lane < cnt ? lane : cnt - 1)];
        int r = 0;
        for (; r + 16 <= cnt; r += 16) {
            unsigned u0 = __shfl(ev, r + q, 64);
            unsigned u1 = __shfl(ev, r + 4 + q, 64);
            unsigned u2 = __shfl(ev, r + 8 + q, 64);
            unsigned u3 = __shfl(ev, r + 12 + q, 64);
            const uint4 h0 = *(const uint4*)&Hin[(size_t)(u0 >> 14) * 64 + l16 * 4];
            const uint4 h1 = *(const uint4*)&Hin[(size_t)(u1 >> 14) * 64 + l16 * 4];
            const uint4 h2 = *(const uint4*)&Hin[(size_t)(u2 >> 14) * 64 + l16 * 4];
            const uint4 h3 = *(const uint4*)&Hin[(size_t)(u3 >> 14) * 64 + l16 * 4];
            h16x2 v01 = u2h(pk16lo(u1 & 0x3fffu, u0 & 0x3fffu));
            h16x2 v23 = u2h(pk16lo(u3 & 0x3fffu, u2 & 0x3fffu));
            a0 = fdot2(v01, u2h(pk16lo(h1.x, h0.x)), a0);
            a0 = fdot2(v23, u2h(pk16lo(h3.x, h2.x)), a0);
            a1 = fdot2(v01, u2h(pk16hi(h1.x, h0.x)), a1);
            a1 = fdot2(v23, u2h(pk16hi(h3.x, h2.x)), a1);
            a2 = fdot2(v01, u2h(pk16lo(h1.y, h0.y)), a2);
            a2 = fdot2(v23, u2h(pk16lo(h3.y, h2.y)), a2);
            a3 = fdot2(v01, u2h(pk16hi(h1.y, h0.y)), a3);
            a3 = fdot2(v23, u2h(pk16hi(h3.y, h2.y)), a3);
            a4 = fdot2(v01, u2h(pk16lo(h1.z, h0.z)), a4);
            a4 = fdot2(v23, u2h(pk16lo(h3.z, h2.z)), a4);
            a5 = fdot2(v01, u2h(pk16hi(h1.z, h0.z)), a5);
            a5 = fdot2(v23, u2h(pk16hi(h3.z, h2.z)), a5);
            a6 = fdot2(v01, u2h(pk16lo(h1.w, h0.w)), a6);
            a6 = fdot2(v23, u2h(pk16lo(h3.w, h2.w)), a6);
            a7 = fdot2(v01, u2h(pk16hi(h1.w, h0.w)), a7);
            a7 = fdot2(v23, u2h(pk16hi(h3.w, h2.w)), a7);
        }
        if (r < cnt) {
            int i0 = r + q, i1 = r + 4 + q, i2 = r + 8 + q, i3 = r + 12 + q;
            unsigned u0 = __shfl(ev, i0 < cnt ? i0 : cnt - 1, 64);
            unsigned u1 = __shfl(ev, i1 < cnt ? i1 : cnt - 1, 64);
            unsigned u2 = __shfl(ev, i2 < cnt ? i2 : cnt - 1, 64);
            unsigned u3 = __shfl(ev, i3 < cnt ? i3 : cnt - 1, 64);
            const uint4 h0 = *(const uint4*)&Hin[(size_t)(u0 >> 14) * 64 + l16 * 4];
            const uint4 h1 = *(const uint4*)&Hin[(size_t)(u1 >> 14) * 64 + l16 * 4];
            const uint4 h2 = *(const uint4*)&Hin[(size_t)(u2 >> 14) * 64 + l16 * 4];
            const uint4 h3 = *(const uint4*)&Hin[(size_t)(u3 >> 14) * 64 + l16 * 4];
            unsigned m0 = (i0 < cnt) ? (u0 & 0x3fffu) : 0u;
            unsigned m1 = (i1 < cnt) ? (u1 & 0x3fffu) : 0u;
            unsigned m2 = (i2 < cnt) ? (u2 & 0x3fffu) : 0u;
            unsigned m3 = (i3 < cnt) ? (u3 & 0x3fffu) : 0u;
            h16x2 v01 = u2h(pk16lo(m1, m0));
            h16x2 v23 = u2h(pk16lo(m3, m2));
            a0 = fdot2(v01, u2h(pk16lo(h1.x, h0.x)), a0);
            a0 = fdot2(v23, u2h(pk16lo(h3.x, h2.x)), a0);
            a1 = fdot2(v01, u2h(pk16hi(h1.x, h0.x)), a1);
            a1 = fdot2(v23, u2h(pk16hi(h3.x, h2.x)), a1);
            a2 = fdot2(v01, u2h(pk16lo(h1.y, h0.y)), a2);
            a2 = fdot2(v23, u2h(pk16lo(h3.y, h2.y)), a2);
            a3 = fdot2(v01, u2h(pk16hi(h1.y, h0.y)), a3);
            a3 = fdot2(v23, u2h(pk16hi(h3.y, h2.y)), a3);
            a4 = fdot2(v01, u2h(pk16lo(h1.z, h0.z)), a4);
            a4 = fdot2(v23, u2h(pk16lo(h3.z, h2.z)), a4);
            a5 = fdot2(v01, u2h(pk16hi(h1.z, h0.z)), a5);
            a5 = fdot2(v23, u2h(pk16hi(h3.z, h2.z)), a5);
            a6 = fdot2(v01, u2h(pk16lo(h1.w, h0.w)), a6);
            a6 = fdot2(v23, u2h(pk16lo(h3.w, h2.w)), a6);
            a7 = fdot2(v01, u2h(pk16hi(h1.w, h0.w)), a7);
            a7 = fdot2(v23, u2h(pk16hi(h3.w, h2.w)), a7);
        }
    }
    a0 += __shfl_xor(a0, 16, 64); a0 += __shfl_xor(a0, 32, 64);
    a1 += __shfl_xor(a1, 16, 64); a1 += __shfl_xor(a1, 32, 64);
    a2 += __shfl_xor(a2, 16, 64); a2 += __shfl_xor(a2, 32, 64);
    a3 += __shfl_xor(a3, 16, 64); a3 += __shfl_xor(a3, 32, 64);
    a4 += __shfl_xor(a4, 16, 64); a4 += __shfl_xor(a4, 32, 64);
    a5 += __shfl_xor(a5, 16, 64); a5 += __shfl_xor(a5, 32, 64);
    a6 += __shfl_xor(a6, 16, 64); a6 += __shfl_xor(a6, 32, 64);
    a7 += __shfl_xor(a7, 16, 64); a7 += __shfl_xor(a7, 32, 64);
    if (q == 0) {
        uint4 p;
        p.x = (f2h_bits(a1) << 16) | f2h_bits(a0);
        p.y = (f2h_bits(a3) << 16) | f2h_bits(a2);
        p.z = (f2h_bits(a5) << 16) | f2h_bits(a4);
        p.w = (f2h_bits(a7) << 16) | f2h_bits(a6);
        *(uint4*)&Ho[(size_t)wid * 64 + l16 * 4] = p;
    }
}

// ------- Final: out = relu(AH@W1 + A2H@W2) @ W_out + b_out, f16 MFMA --------
__global__ __launch_bounds__(256) void k_gemm_out(const unsigned short* __restrict__ AH,
                                                  const unsigned short* __restrict__ A2H,
                                                  const unsigned short* __restrict__ Wt1,
                                                  const unsigned short* __restrict__ Wt2,
                                                  const float* __restrict__ Wout,
                                                  const float* __restrict__ bout,
                                                  float* __restrict__ out) {
    __shared__ unsigned short lds[2][64 * LROW];
    __shared__ float part[4][64];
    int tid = threadIdx.x;
    int lane = tid & 63, wv = tid >> 6;
    int quad = lane >> 4, c16 = lane & 15;

    f16x8 w1f[2][4], w2f[2][4];
    float wo[2];
#pragma unroll
    for (int nt = 0; nt < 2; nt++) {
        int ng = wv * 2 + nt;
        wo[nt] = Wout[ng * 16 + c16];
#pragma unroll
        for (int kc = 0; kc < 4; kc++) {
            w1f[nt][kc] = *(const f16x8*)&Wt1[(ng * 16 + c16) * 128 + kc * 32 + quad * 8];
            w2f[nt][kc] = *(const f16x8*)&Wt2[(ng * 16 + c16) * 128 + kc * 32 + quad * 8];
        }
    }
    float bo = bout[0];

    int tilebase = blockIdx.x * 64;
    const uint4* Ag = (const uint4*)(AH + (size_t)tilebase * 128);
    const uint4* Bg = (const uint4*)(A2H + (size_t)tilebase * 128);
#pragma unroll
    for (int i = 0; i < 4; i++) {
        int c = tid + i * 256;
        int r = c >> 4, o = c & 15;
        *(uint4*)&lds[0][r * LROW + o * 8] = Ag[c];
        *(uint4*)&lds[1][r * LROW + o * 8] = Bg[c];
    }
    __syncthreads();

    f32x4 acc[4][2] = {};
#pragma unroll
    for (int t4 = 0; t4 < 4; t4++) {
#pragma unroll
        for (int kc = 0; kc < 4; kc++) {
            f16x8 afA = *(const f16x8*)&lds[0][(t4 * 16 + c16) * LROW + kc * 32 + quad * 8];
            f16x8 afB = *(const f16x8*)&lds[1][(t4 * 16 + c16) * LROW + kc * 32 + quad * 8];
#pragma unroll
            for (int nt = 0; nt < 2; nt++) {
                acc[t4][nt] = __builtin_amdgcn_mfma_f32_16x16x32_f16(afA, w1f[nt][kc],
                                                                    acc[t4][nt], 0, 0, 0);
                acc[t4][nt] = __builtin_amdgcn_mfma_f32_16x16x32_f16(afB, w2f[nt][kc],
                                                                    acc[t4][nt], 0, 0, 0);
            }
        }
    }

#pragma unroll
    for (int t4 = 0; t4 < 4; t4++) {
        float p[4];
#pragma unroll
        for (int r = 0; r < 4; r++)
            p[r] = fmaxf(acc[t4][0][r], 0.f) * wo[0] + fmaxf(acc[t4][1][r], 0.f) * wo[1];
#pragma unroll
        for (int m = 1; m < 16; m <<= 1)
#pragma unroll
            for (int r = 0; r < 4; r++) p[r] += __shfl_xor(p[r], m, 64);
        if (c16 == 0)
#pragma unroll
            for (int r = 0; r < 4; r++) part[wv][t4 * 16 + quad * 4 + r] = p[r];
    }
    __syncthreads();
    if (tid < 64) {
        int orow = tilebase + tid;
        if (orow < N_NODES)
            out[orow] = part[0][tid] + part[1][tid] + part[2][tid] + part[3][tid] + bo;
    }
}

// ---------------- launch ----------------

extern "C" void kernel_launch(void* const* d_in, const int* in_sizes, int n_in,
                              void* d_out, int out_size, void* d_ws, size_t ws_size,
                              hipStream_t stream) {
    const float* X    = (const float*)d_in[0];
    const int*   row  = (const int*)d_in[1];
    const int*   col  = (const int*)d_in[2];
    const float* vals = (const float*)d_in[3];
    const float* W_in = (const float*)d_in[4];
    const float* b_in = (const float*)d_in[5];
    const float* W1   = (const float*)d_in[6];
    const float* W2   = (const float*)d_in[7];
    const float* Wout = (const float*)d_in[8];
    const float* bout = (const float*)d_in[9];
    float* out = (float*)d_out;

    char* ws = (char*)d_ws;
    size_t off = 0;
    auto alloc = [&](size_t bytes) -> void* {
        void* p = ws + off;
        off += (bytes + 511) & ~(size_t)511;
        return p;
    };
    unsigned short* Hb  = (unsigned short*)alloc((size_t)N_NODES * 128 * 2);  // H f16
    unsigned short* AHb = (unsigned short*)alloc((size_t)N_NODES * 128 * 2);  // AH f16
    unsigned short* A2b = (unsigned short*)alloc((size_t)N_NODES * 128 * 2);  // A2H f16
    unsigned* evf  = (unsigned*)alloc((size_t)N_EDGES * 4);
    int2* grouped  = (int2*)alloc((size_t)N_EDGES * 8);
    unsigned short* Wtin = (unsigned short*)alloc(128 * 128 * 2);
    unsigned short* Wt1  = (unsigned short*)alloc(128 * 128 * 2);
    unsigned short* Wt2  = (unsigned short*)alloc(128 * 128 * 2);
    int*   hmat    = (int*)alloc((size_t)NCHUNK * NBUCK * 4);
    int*   bases   = (int*)alloc((size_t)NCHUNK * NBUCK * 4);
    int*   bstart  = (int*)alloc(512 * 4);
    int*   row_ptr = (int*)alloc((size_t)(N_NODES + 256) * 4);

    k_prep<<<NCHUNK + 192, 256, 0, stream>>>(row, hmat, W_in, W1, W2, Wtin, Wt1, Wt2);
    k_colscanB<<<NBUCK + 1, 512, 0, stream>>>(hmat, bases, bstart);
    k_binC<<<NCHUNK, 256, 0, stream>>>(row, col, vals, bstart, bases, grouped);
    k_binD<<<NBUCK, 256, 0, stream>>>(grouped, bstart, evf, row_ptr);

    int gblk = (N_NODES + 63) / 64;  // 1563
    k_gemm_in<<<gblk, 256, 0, stream>>>(X, Wtin, b_in, Hb);

    int sblk = (N_NODES + 3) / 4;  // 4 waves/block, 1 row/wave
    k_spmm<<<sblk, 256, 0, stream>>>(row_ptr, evf, (const unsigned*)Hb, (unsigned*)AHb);
    k_spmm<<<sblk, 256, 0, stream>>>(row_ptr, evf, (const unsigned*)AHb, (unsigned*)A2b);

    k_gemm_out<<<gblk, 256, 0, stream>>>(AHb, A2b, Wt1, Wt2, Wout, bout, out);
}